// Round 1
// baseline (291.323 us; speedup 1.0000x reference)
//
#include <hip/hip_runtime.h>

// ============================================================================
// AttenPool reduction: the reference's softmax over patch-axis L is summed
// over L and broadcast -> exactly 1.0. The whole query branch is dead.
//   out[b,c,i,j] = (1-a)*( sumpool4(conv3(BN(x),wv)) + 16*bv[c] ) + a*sumpool4(x)
// sumpool4 o conv3 == 6x6 stride-4 conv with W6[a,b] = sum of wv taps with
// a=dy+ky, b=dx+kx (dy,dx in 0..3). BN scale folds into W6; BN offset becomes
// a per-(outch, border-class) constant (zero padding => 9 classes).
// ============================================================================

constexpr int Bn = 16, Cn = 64, Hn = 128, Wn = 128, NP = 32;
constexpr float EPSV = 1e-5f;

// ---- precompute W6T[k][o], k = i*36 + a*6 + b, scaled by (1-alpha)*s0[i] ----
__global__ void k_w6t(const float* __restrict__ wv, const float* __restrict__ g0,
                      const float* __restrict__ v0, const float* __restrict__ alpha,
                      float* __restrict__ W6T) {
  int t = blockIdx.x * blockDim.x + threadIdx.x;
  if (t >= Cn * Cn) return;
  int o = t >> 6, i = t & 63;
  float s0 = g0[i] / sqrtf(v0[i] + EPSV);
  float oma = 1.0f - alpha[0];
  float wl[3][3];
#pragma unroll
  for (int ky = 0; ky < 3; ++ky)
#pragma unroll
    for (int kx = 0; kx < 3; ++kx)
      wl[ky][kx] = wv[((o * Cn + i) * 3 + ky) * 3 + kx];
#pragma unroll
  for (int a = 0; a < 6; ++a) {
    int klo = (a - 3 < 0) ? 0 : a - 3, khi = (a < 2) ? a : 2;
#pragma unroll
    for (int b = 0; b < 6; ++b) {
      int llo = (b - 3 < 0) ? 0 : b - 3, lhi = (b < 2) ? b : 2;
      float s = 0.f;
      for (int ky = klo; ky <= khi; ++ky)
        for (int kx = llo; kx <= lhi; ++kx) s += wl[ky][kx];
      W6T[(i * 36 + a * 6 + b) * 64 + o] = s * s0 * oma;
    }
  }
}

// ---- border-class offset table: offC[o][ic][jc] =
//      (1-a)*( sum_i o0_i * sum_{(a,b) in-range(ic,jc)} W6[o][i][a][b] + 16*bv[o] )
__global__ void k_offc(const float* __restrict__ wv, const float* __restrict__ g0,
                       const float* __restrict__ b0, const float* __restrict__ m0,
                       const float* __restrict__ v0, const float* __restrict__ bv,
                       const float* __restrict__ alpha, float* __restrict__ offC) {
  int o = threadIdx.x;
  if (o >= Cn) return;
  float acc[3][3] = {{0.f, 0.f, 0.f}, {0.f, 0.f, 0.f}, {0.f, 0.f, 0.f}};
  for (int i = 0; i < Cn; ++i) {
    float s0 = g0[i] / sqrtf(v0[i] + EPSV);
    float o0 = b0[i] - m0[i] * s0;
    float wl[3][3];
    for (int ky = 0; ky < 3; ++ky)
      for (int kx = 0; kx < 3; ++kx)
        wl[ky][kx] = wv[((o * Cn + i) * 3 + ky) * 3 + kx];
    float w6[6][6];
    for (int a = 0; a < 6; ++a) {
      int klo = (a - 3 < 0) ? 0 : a - 3, khi = (a < 2) ? a : 2;
      for (int bq = 0; bq < 6; ++bq) {
        int llo = (bq - 3 < 0) ? 0 : bq - 3, lhi = (bq < 2) ? bq : 2;
        float s = 0.f;
        for (int ky = klo; ky <= khi; ++ky)
          for (int kx = llo; kx <= lhi; ++kx) s += wl[ky][kx];
        w6[a][bq] = s;
      }
    }
    // row sums over b-ranges: jc=0 -> b in [1,5], jc=1 -> [0,5], jc=2 -> [0,4]
    float rs[6][3];
    for (int a = 0; a < 6; ++a) {
      float s1 = 0.f, s2 = 0.f, s3 = 0.f;
      for (int bq = 0; bq < 6; ++bq) {
        float v = w6[a][bq];
        if (bq >= 1) s1 += v;
        s2 += v;
        if (bq <= 4) s3 += v;
      }
      rs[a][0] = s1; rs[a][1] = s2; rs[a][2] = s3;
    }
    for (int jc = 0; jc < 3; ++jc) {
      float sA = 0.f, sB = 0.f, sC = 0.f;
      for (int a = 0; a < 6; ++a) {
        float v = rs[a][jc];
        if (a >= 1) sA += v;
        sB += v;
        if (a <= 4) sC += v;
      }
      acc[0][jc] += o0 * sA;  // ic=0: a in [1,5]
      acc[1][jc] += o0 * sB;  // ic=1: a in [0,5]
      acc[2][jc] += o0 * sC;  // ic=2: a in [0,4]
    }
  }
  float oma = 1.f - alpha[0];
  for (int ic = 0; ic < 3; ++ic)
    for (int jc = 0; jc < 3; ++jc)
      offC[(o * 3 + ic) * 3 + jc] = oma * (acc[ic][jc] + 16.f * bv[o]);
}

// ---- out = alpha * sum over 4x4 patch of x (memory-bound init pass) ----
__global__ void k_init(const float* __restrict__ x, const float* __restrict__ alpha,
                       float* __restrict__ out) {
  int t = blockIdx.x * blockDim.x + threadIdx.x;
  if (t >= Bn * Cn * NP * NP) return;
  int pj = t & 31, pi = (t >> 5) & 31, bc = t >> 10;
  const float* p = x + ((size_t)bc * Hn + pi * 4) * Wn + pj * 4;
  float s = 0.f;
#pragma unroll
  for (int r = 0; r < 4; ++r) {
    float4 v = *(const float4*)(p + (size_t)r * Wn);
    s += (v.x + v.y) + (v.z + v.w);
  }
  out[t] = alpha[0] * s;
}

// ---- main: 6x6 stride-4 conv as register-blocked GEMM on LDS tiles ----
// Block: one batch b, 8x8 patch tile, all 64 out channels. 256 threads:
// thread = (tm in 0..15 -> 4 out-ch) x (tn in 0..15 -> 4 patches).
// LDS x tile: 4 input ch x 34x34 (halo=1 each side), row-padded to 35 floats
// so the wave's x-reads land on 16 distinct banks (4-lane broadcast, no conflict).
__global__ __launch_bounds__(256) void k_conv(const float* __restrict__ x,
    const float* __restrict__ W6T, const float* __restrict__ offC,
    float* __restrict__ out) {
  __shared__ float xs[4][34][35];
  __shared__ float ws[144][64];
  const int b = blockIdx.z;
  const int pi0 = blockIdx.y * 8, pj0 = blockIdx.x * 8;
  const int tid = threadIdx.x;
  const int lane = tid & 63;
  const int tn = lane & 15;
  const int tm = (tid >> 6) * 4 + (lane >> 4);
  const int obase = tm * 4;
  const int prow = tn >> 1;          // patch row within tile (0..7)
  const int pcol0 = (tn & 1) * 16;   // pixel col base within tile (0 or 16)
  float acc[4][4] = {};
  const int grow0 = pi0 * 4 - 1, gcol0 = pj0 * 4 - 1;
  const float* xb = x + (size_t)b * Cn * Hn * Wn;

  for (int cib = 0; cib < Cn; cib += 4) {
    __syncthreads();
    // stage x tile (zero halo outside image = conv zero padding in xn-space)
    for (int idx = tid; idx < 4 * 34 * 34; idx += 256) {
      int ch = idx / 1156;
      int rem = idx - ch * 1156;
      int r = rem / 34;
      int c2 = rem - r * 34;
      int gr = grow0 + r, gc = gcol0 + c2;
      float v = 0.f;
      if ((unsigned)gr < 128u && (unsigned)gc < 128u)
        v = xb[(size_t)(cib + ch) * (Hn * Wn) + gr * Wn + gc];
      xs[ch][r][c2] = v;
    }
    // stage weight chunk: contiguous 144x64 floats
    {
      const float4* src = (const float4*)(W6T + (size_t)cib * 36 * 64);
      float4* dst = (float4*)&ws[0][0];
      for (int idx = tid; idx < 144 * 16; idx += 256) dst[idx] = src[idx];
    }
    __syncthreads();

    for (int ci = 0; ci < 4; ++ci) {
      const float* xsc = &xs[ci][0][0];
      const float* wsc = &ws[ci * 36][0];
#pragma unroll
      for (int a = 0; a < 6; ++a) {
#pragma unroll
        for (int bb = 0; bb < 6; ++bb) {
          const float4 w = *(const float4*)(wsc + (a * 6 + bb) * 64 + obase);
          const float* xr = xsc + (prow * 4 + a) * 35 + pcol0 + bb;
          float xv0 = xr[0], xv1 = xr[4], xv2 = xr[8], xv3 = xr[12];
          acc[0][0] += w.x * xv0; acc[0][1] += w.x * xv1; acc[0][2] += w.x * xv2; acc[0][3] += w.x * xv3;
          acc[1][0] += w.y * xv0; acc[1][1] += w.y * xv1; acc[1][2] += w.y * xv2; acc[1][3] += w.y * xv3;
          acc[2][0] += w.z * xv0; acc[2][1] += w.z * xv1; acc[2][2] += w.z * xv2; acc[2][3] += w.z * xv3;
          acc[3][0] += w.w * xv0; acc[3][1] += w.w * xv1; acc[3][2] += w.w * xv2; acc[3][3] += w.w * xv3;
        }
      }
    }
  }

  // epilogue: accumulate conv part + border-class constant into out
  const int pig = pi0 + prow;
  const int icl = (pig == 0) ? 0 : ((pig == 31) ? 2 : 1);
#pragma unroll
  for (int oo = 0; oo < 4; ++oo) {
    const int o = obase + oo;
#pragma unroll
    for (int e = 0; e < 4; ++e) {
      const int pjg = pj0 + (tn & 1) * 4 + e;
      const int jcl = (pjg == 0) ? 0 : ((pjg == 31) ? 2 : 1);
      size_t oi = (((size_t)b * Cn + o) * NP + pig) * NP + pjg;
      out[oi] += acc[oo][e] + offC[(o * 3 + icl) * 3 + jcl];
    }
  }
}

extern "C" void kernel_launch(void* const* d_in, const int* in_sizes, int n_in,
                              void* d_out, int out_size, void* d_ws, size_t ws_size,
                              hipStream_t stream) {
  const float* x     = (const float*)d_in[0];
  const float* g0    = (const float*)d_in[1];
  const float* b0    = (const float*)d_in[2];
  const float* m0    = (const float*)d_in[3];
  const float* v0    = (const float*)d_in[4];
  const float* wv    = (const float*)d_in[15];
  const float* bv    = (const float*)d_in[16];
  const float* alpha = (const float*)d_in[17];
  float* out = (float*)d_out;

  float* W6T  = (float*)d_ws;          // 2304*64 floats = 576 KB
  float* offC = W6T + 2304 * 64;       // 64*9 floats

  k_w6t<<<16, 256, 0, stream>>>(wv, g0, v0, alpha, W6T);
  k_offc<<<1, 64, 0, stream>>>(wv, g0, b0, m0, v0, bv, alpha, offC);
  k_init<<<(Bn * Cn * NP * NP) / 256, 256, 0, stream>>>(x, alpha, out);
  dim3 grid(NP / 8, NP / 8, Bn);
  k_conv<<<grid, 256, 0, stream>>>(x, W6T, offC, out);
}

// Round 5
// 68.013 us; speedup vs baseline: 4.2834x; 4.2834x over previous
//
#include <hip/hip_runtime.h>

// ============================================================================
// AttenPool: softmax-over-L summed over L == 1, so
//   out[b,c,P] = (1-a)*( sumpool4(conv3(BN(x),wv))[c,P] + 16*bv[c] )
//                + a*sumpool4(x)[c,P]
// sumpool4 o conv3 == 6x6 stride-4 conv (W6); BN scale folds into W6; BN offset
// -> per-(outch, border-class) constant (9 classes). The per-channel a*x
// patch-sum is ALSO a 6x6 stride-4 conv: weight a*delta_{o,i} on interior taps
// (a,b in 1..4) -> folded into the same weight table (round-4 bug: patchsum
// was summed over channels; identical absmax across different MFMA layouts
// proved the MFMA path was fine and the patchsum was the error).
// Conv = implicit GEMM on mfma_f32_16x16x32_bf16; A and B fragments use the
// IDENTICAL (lane-group, elem)->(tap, channel) map so any internal HW
// k-permutation cancels. LDS x tile [pixel][16ch] bf16, double-buffered,
// bijective swizzle addr = (p*32+hh*16) ^ (((p>>2)&7)<<4).
// ============================================================================

typedef short short8 __attribute__((ext_vector_type(8)));
typedef float f32x4 __attribute__((ext_vector_type(4)));

constexpr int Bn = 16, Cn = 64, Hn = 128, Wn = 128, NP = 32;
constexpr float EPSV = 1e-5f;

__device__ __forceinline__ unsigned short bf16r(float f) {
  unsigned u = __builtin_bit_cast(unsigned, f);
  u += 0x7fffu + ((u >> 16) & 1u);
  return (unsigned short)(u >> 16);
}
__device__ __forceinline__ int swz(int p, int hh) {
  return (p * 32 + hh * 16) ^ (((p >> 2) & 7) << 4);
}

// ---- weight table: short8 idx = s*1024 + chunk*256 + (mt*64 + g*16 + r)
//      elem j: o = mt*16+r, tap t36 = 2s + (g>>1), i = chunk*16 + (g&1)*8 + j
//      value = W6[o][i][t36]*s0[i]*(1-a)  +  a*delta_{o,i}*[tap interior]
__global__ void k_wa(const float* __restrict__ wv, const float* __restrict__ g0,
                     const float* __restrict__ v0, const float* __restrict__ alpha,
                     unsigned short* __restrict__ WA) {
  int t = blockIdx.x * 256 + threadIdx.x;
  if (t >= Cn * Cn) return;
  int o = t >> 6, i = t & 63;
  float s0 = g0[i] * rsqrtf(v0[i] + EPSV);
  float al = alpha[0];
  float oma = 1.0f - al;
  float wl[3][3];
#pragma unroll
  for (int ky = 0; ky < 3; ++ky)
#pragma unroll
    for (int kx = 0; kx < 3; ++kx)
      wl[ky][kx] = wv[((o * Cn + i) * 3 + ky) * 3 + kx];
#pragma unroll
  for (int a = 0; a < 6; ++a) {
    int klo = (a - 3 < 0) ? 0 : a - 3, khi = (a < 2) ? a : 2;
#pragma unroll
    for (int b = 0; b < 6; ++b) {
      int llo = (b - 3 < 0) ? 0 : b - 3, lhi = (b < 2) ? b : 2;
      float s = 0.f;
      for (int ky = klo; ky <= khi; ++ky)
        for (int kx = llo; kx <= lhi; ++kx) s += wl[ky][kx];
      float val = s * s0 * oma;
      if (o == i && a >= 1 && a <= 4 && b >= 1 && b <= 4) val += al;
      int t36 = a * 6 + b;
      int g = (t36 & 1) * 2 + ((i >> 3) & 1);
      int idx8 = (t36 >> 1) * 1024 + (i >> 4) * 256 + ((o >> 4) * 64 + g * 16 + (o & 15));
      WA[idx8 * 8 + (i & 7)] = bf16r(val);
    }
  }
}

// ---- border-class offsets: offC[cls][o] ----
__global__ void k_offc(const float* __restrict__ wv, const float* __restrict__ g0,
                       const float* __restrict__ b0, const float* __restrict__ m0,
                       const float* __restrict__ v0, const float* __restrict__ bv,
                       const float* __restrict__ alpha, float* __restrict__ offC) {
  int o = threadIdx.x;
  int cls = blockIdx.x;  // 0..8
  int ic = cls / 3, jc = cls % 3;
  const int N0[3] = {3, 4, 4}, N1[3] = {4, 4, 4}, N2[3] = {4, 4, 3};
  const int* Na = (ic == 0) ? N0 : ((ic == 1) ? N1 : N2);
  const int* Nb = (jc == 0) ? N0 : ((jc == 1) ? N1 : N2);
  float acc = 0.f;
  for (int i = 0; i < Cn; ++i) {
    float s0 = g0[i] * rsqrtf(v0[i] + EPSV);
    float o0 = b0[i] - m0[i] * s0;
    float s = 0.f;
#pragma unroll
    for (int ky = 0; ky < 3; ++ky) {
      float rs = 0.f;
#pragma unroll
      for (int kx = 0; kx < 3; ++kx)
        rs += wv[((o * Cn + i) * 3 + ky) * 3 + kx] * (float)Nb[kx];
      s += rs * (float)Na[ky];
    }
    acc += o0 * s;
  }
  offC[cls * 64 + o] = (1.f - alpha[0]) * (acc + 16.f * bv[o]);
}

// ---- fused MFMA conv (+ diag alpha term) + offset epilogue ----
__global__ __launch_bounds__(256, 1) void k_conv(const float* __restrict__ x,
    const unsigned short* __restrict__ WA, const float* __restrict__ offC,
    float* __restrict__ out) {
  __shared__ alignas(128) unsigned short xs[2][18496];  // 2 x 36992 B

  const int tid = threadIdx.x;
  const int b = blockIdx.z, by = blockIdx.y, bx = blockIdx.x;
  const int lane = tid & 63, w = tid >> 6;
  const int r = lane & 15, g = lane >> 4;       // g in 0..3
  const int g1 = g >> 1, hh16 = (g & 1) * 16;
  const float* xb = x + (size_t)b * (Cn * Hn * Wn);
  const int grow0 = by * 32 - 1, gcol0 = bx * 32 - 1;

  // staging slot precompute: slot s = hh*1156 + pixel, pixel = rr*34+cc
  int sg[10], sl[10], sv[10];
#pragma unroll
  for (int j = 0; j < 10; ++j) {
    int s = tid + j * 256;
    int valid = (s < 2312);
    int hh = (s >= 1156) ? 1 : 0;
    int pixel = valid ? (s - hh * 1156) : 0;
    int rr = pixel / 34;
    int cc = pixel - rr * 34;
    int gr = grow0 + rr, gc = gcol0 + cc;
    int inb = valid && ((unsigned)gr < 128u) && ((unsigned)gc < 128u);
    sg[j] = hh * (8 * 16384) + gr * 128 + gc;
    sl[j] = swz(pixel, hh);
    sv[j] = valid ? (inb ? 2 : 1) : 0;
  }

  // B-frag base: patch P = nt*16 + r -> pi = nt*2 + (r>>3), pj = r&7
  const int pbase = (r >> 3) * 136 + (r & 7) * 4 + g1;

  f32x4 acc[4];
#pragma unroll
  for (int t = 0; t < 4; ++t)
#pragma unroll
    for (int i = 0; i < 4; ++i) acc[t][i] = 0.f;
  float st[10][8];

  auto LOAD = [&](int ch) {
    const float* xc = xb + (size_t)(ch * 16) * 16384;
#pragma unroll
    for (int j = 0; j < 10; ++j)
#pragma unroll
      for (int k = 0; k < 8; ++k)
        st[j][k] = (sv[j] == 2) ? xc[sg[j] + k * 16384] : 0.f;
  };
  auto WRITE = [&](int ch) {
    char* base = (char*)&xs[ch & 1][0];
#pragma unroll
    for (int j = 0; j < 10; ++j) {
      if (sv[j]) {
        short8 w8;
#pragma unroll
        for (int k = 0; k < 8; ++k) w8[k] = (short)bf16r(st[j][k]);
        *(short8*)(base + sl[j]) = w8;
      }
    }
  };
  auto COMPUTE = [&](int ch) {
    const char* base = (const char*)&xs[ch & 1][0];
    const short8* wv8 = (const short8*)WA;
    const int lc = ch * 256 + tid;  // = ch*256 + w*64 + g*16 + r
    short8 af[18];
#pragma unroll
    for (int s = 0; s < 18; ++s) af[s] = wv8[s * 1024 + lc];
#pragma unroll
    for (int s = 0; s < 18; ++s) {
      const int toff = ((2 * s) / 6) * 34 + (2 * s) % 6;  // compile-time
      int p = pbase + toff;
      int a0 = (p * 32) ^ (((p >> 2) & 7) << 4) ^ hh16;
      int a1 = (a0 + 8704) ^ 64;          // swz(p+272) identity
      int a2 = a0 + 17408;                // swz(p+544) identity
      int a3 = (a2 + 8704) ^ 64;
      short8 bv0 = *(const short8*)(base + a0);
      short8 bv1 = *(const short8*)(base + a1);
      short8 bv2 = *(const short8*)(base + a2);
      short8 bv3 = *(const short8*)(base + a3);
      acc[0] = __builtin_amdgcn_mfma_f32_16x16x32_bf16(af[s], bv0, acc[0], 0, 0, 0);
      acc[1] = __builtin_amdgcn_mfma_f32_16x16x32_bf16(af[s], bv1, acc[1], 0, 0, 0);
      acc[2] = __builtin_amdgcn_mfma_f32_16x16x32_bf16(af[s], bv2, acc[2], 0, 0, 0);
      acc[3] = __builtin_amdgcn_mfma_f32_16x16x32_bf16(af[s], bv3, acc[3], 0, 0, 0);
    }
  };

  LOAD(0);
  WRITE(0);
  __syncthreads();
#pragma unroll
  for (int c = 0; c < 4; ++c) {
    if (c < 3) LOAD(c + 1);   // issue next-chunk global loads early (T14)
    COMPUTE(c);               // mfma while loads are in flight
    if (c < 3) {
      WRITE(c + 1);           // vmcnt + cvt + ds_write (other buffer)
      __syncthreads();
    }
  }

  // epilogue: D col = lane&15 = r -> patch P = nt*16+r; row = g*4+reg -> o
#pragma unroll
  for (int nt = 0; nt < 4; ++nt) {
    const int P = nt * 16 + r;
    const int pig = by * 8 + (P >> 3), pjg = bx * 8 + (P & 7);
    const int icl = (pig == 0) ? 0 : ((pig == 31) ? 2 : 1);
    const int jcl = (pjg == 0) ? 0 : ((pjg == 31) ? 2 : 1);
    const float* offr = offC + (icl * 3 + jcl) * 64;
    float* ob = out + (((size_t)b * 64) * NP + pig) * NP + pjg;
#pragma unroll
    for (int reg = 0; reg < 4; ++reg) {
      const int o = w * 16 + g * 4 + reg;
      ob[(size_t)o * 1024] = acc[nt][reg] + offr[o];
    }
  }
}

extern "C" void kernel_launch(void* const* d_in, const int* in_sizes, int n_in,
                              void* d_out, int out_size, void* d_ws, size_t ws_size,
                              hipStream_t stream) {
  const float* x     = (const float*)d_in[0];
  const float* g0    = (const float*)d_in[1];
  const float* b0    = (const float*)d_in[2];
  const float* m0    = (const float*)d_in[3];
  const float* v0    = (const float*)d_in[4];
  const float* wv    = (const float*)d_in[15];
  const float* bv    = (const float*)d_in[16];
  const float* alpha = (const float*)d_in[17];
  float* out = (float*)d_out;

  unsigned short* WA = (unsigned short*)d_ws;          // 18*1024 short8 = 288 KB
  float* offC = (float*)(WA + 18 * 1024 * 8);          // 9*64 floats

  k_wa<<<16, 256, 0, stream>>>(wv, g0, v0, alpha, WA);
  k_offc<<<9, 64, 0, stream>>>(wv, g0, b0, m0, v0, bv, alpha, offC);
  dim3 grid(NP / 8, NP / 8, Bn);
  k_conv<<<grid, 256, 0, stream>>>(x, WA, offC, out);
}